// Round 6
// baseline (131.715 us; speedup 1.0000x reference)
//
#include <hip/hip_runtime.h>

// B=32, N=512, D=256, M=64, HID=256, H2=128, T=16384, rows R=B*T=524288
typedef _Float16 f16;
typedef f16  f16x2 __attribute__((ext_vector_type(2)));
typedef f16  f16x8 __attribute__((ext_vector_type(8)));
typedef float f32x16 __attribute__((ext_vector_type(16)));
typedef unsigned int u32;

#define MFMA32 __builtin_amdgcn_mfma_f32_32x32x16_f16
#define NT 4   // row-tiles (32 rows) per wave

static __device__ __forceinline__ f16x8 cvt8(float4 a, float4 b) {
    f16x8 v;
    v[0]=(f16)a.x; v[1]=(f16)a.y; v[2]=(f16)a.z; v[3]=(f16)a.w;
    v[4]=(f16)b.x; v[5]=(f16)b.y; v[6]=(f16)b.z; v[7]=(f16)b.w;
    return v;
}
static __device__ __forceinline__ u32 pack2(float a, float b) {
    f16x2 p; p[0]=(f16)a; p[1]=(f16)b;
    return __builtin_bit_cast(u32, p);
}
// packed f16 add / relu (VOP3P)
static __device__ __forceinline__ u32 pk_add(u32 a, u32 b) {
    u32 d; asm("v_pk_add_f16 %0, %1, %2" : "=v"(d) : "v"(a), "v"(b)); return d;
}
static __device__ __forceinline__ u32 pk_relu(u32 a) {
    u32 d; asm("v_pk_max_f16 %0, %1, 0" : "=v"(d) : "v"(a)); return d;
}

// ---------------------------------------------------------------------------
// Prepack: W1a (256x256), W1b (64x256), W2 (256x128) -> f16 MFMA A-operand
// fragment layout for 32x32x16: frag[mt][ks][lane][j] = W[k][col],
// k = 16*ks + 8*(lane>>5) + j, col = 32*mt + (lane&31).
// ---------------------------------------------------------------------------
__global__ __launch_bounds__(256) void prepack(
    const float* __restrict__ W1, const float* __restrict__ W2,
    f16* __restrict__ pa, f16* __restrict__ pb, f16* __restrict__ pc)
{
    const int idx = blockIdx.x * 256 + threadIdx.x;   // grid covers 114688
    int rel, fid, mt, ks;
    const int lane = (idx >> 3) & 63;
    const int j    = idx & 7;
    const int g8   = ((lane >> 5) << 3) + j;          // 8*(lane>>5)+j
    const int ln   = lane & 31;
    if (idx < 65536) {                 // W1a: [8 mt][16 ks]
        rel = idx; fid = rel >> 9; mt = fid >> 4; ks = fid & 15;
        int k = 16 * ks + g8, col = 32 * mt + ln;
        pa[rel] = (f16)W1[k * 256 + col];
    } else if (idx < 81920) {          // W1b: [8 mt][4 ks]
        rel = idx - 65536; fid = rel >> 9; mt = fid >> 2; ks = fid & 3;
        int k = 16 * ks + g8, col = 32 * mt + ln;
        pb[rel] = (f16)W1[(256 + k) * 256 + col];
    } else {                           // W2: [4 mt][16 ks]
        rel = idx - 81920; fid = rel >> 9; mt = fid >> 4; ks = fid & 15;
        int k = 16 * ks + g8, col = 32 * mt + ln;
        pc[rel] = (f16)W2[k * 128 + col];
    }
}

// ---------------------------------------------------------------------------
// Kernel 1: A[ir][c] = sum_k h[ir][k] * W1a[k][c] + b1[c], stored f16 in a
// gather-friendly permuted layout: uint2 index = ir*64 + g*32 + mt*4 + q.
// ---------------------------------------------------------------------------
__global__ __launch_bounds__(256) void ainit(
    const float* __restrict__ H,       // [16384, 256]
    const f16x8* __restrict__ pW1a,    // [8][16][64] frags
    const float* __restrict__ B1,      // [256]
    f16* __restrict__ Af)              // [16384, 256] permuted
{
    const int tid = threadIdx.x, wid = tid >> 6, lane = tid & 63;
    const int g = lane >> 5, ln = lane & 31;
    const long ir = (long)blockIdx.x * 32 + ln;

    const float4* h4 = (const float4*)(H + ir * 256);
    f16x8 hf[16];
    #pragma unroll
    for (int ks = 0; ks < 16; ++ks)
        hf[ks] = cvt8(h4[4 * ks + 2 * g], h4[4 * ks + 2 * g + 1]);

    const float4* b14 = (const float4*)B1;
    #pragma unroll
    for (int mi = 0; mi < 2; ++mi) {
        const int mt = wid * 2 + mi;
        f32x16 acc;
        #pragma unroll
        for (int q = 0; q < 4; ++q) {
            float4 bv = b14[8 * mt + 2 * q + g];
            acc[4*q+0] = bv.x; acc[4*q+1] = bv.y; acc[4*q+2] = bv.z; acc[4*q+3] = bv.w;
        }
        #pragma unroll
        for (int ks = 0; ks < 16; ++ks)
            acc = MFMA32(pW1a[(mt * 16 + ks) * 64 + lane], hf[ks], acc, 0, 0, 0);
        #pragma unroll
        for (int q = 0; q < 4; ++q) {
            uint2 w;
            w.x = pack2(acc[4*q+0], acc[4*q+1]);
            w.y = pack2(acc[4*q+2], acc[4*q+3]);
            ((uint2*)Af)[ir * 64 + g * 32 + mt * 4 + q] = w;
        }
    }
}

// ---------------------------------------------------------------------------
// Fused: h1 = relu(me@W1b + A[seg]); h2 = relu(h1@W2 + b2); out = h2@W3 + b3
// 512 blocks x 8 waves, NT=4 tiles/wave.
//  - W1b (32 frags) held in REGISTERS per wave (loop-invariant) -> layer-1
//    is a pure-register MFMA stream, zero operand latency.
//  - W2 in 64 KB LDS (only LDS traffic: 64 reads/tile).
//  - Af gathered via depth-2-mt rolling register prefetch (~600 cyc cover).
//  - ME loaded JIT at tile start. No barriers in main loop.
// ---------------------------------------------------------------------------
__global__ __launch_bounds__(512, 2) void fused_mlp(
    const float* __restrict__ ME,      // [524288, 64]
    const int*   __restrict__ SEG,     // [16384]
    const f16*   __restrict__ Af,      // [16384, 256] permuted
    const f16x8* __restrict__ pW1b,    // [8][4][64] frags
    const f16x8* __restrict__ pW2,     // [4][16][64] frags
    const float* __restrict__ B2,      // [128]
    const float* __restrict__ W3,      // [128]
    const float* __restrict__ B3,      // [1]
    float* __restrict__ OUT)           // [524288]
{
    __shared__ f16x8 sW2[4096];        // 64 KB
    const int tid = threadIdx.x, wid = tid >> 6, lane = tid & 63;
    const int g = lane >> 5, ln = lane & 31;

    #pragma unroll
    for (int i = 0; i < 8; ++i) sW2[i * 512 + tid] = pW2[i * 512 + tid];

    // W1b: loop-invariant, one copy per wave in registers (128 VGPR)
    f16x8 w1b[32];
    #pragma unroll
    for (int f = 0; f < 32; ++f) w1b[f] = pW1b[f * 64 + lane];

    __syncthreads();

    // XCD-bijective block swizzle (512 % 8 == 0)
    const int bswz = (blockIdx.x & 7) * 64 + (blockIdx.x >> 3);
    const long gwave    = (long)bswz * 8 + wid;       // 4096 waves
    const long row_base = gwave * (NT * 32);          // 128 rows per wave

    // segment-gather rows for all NT tiles
    int arow[NT];
    #pragma unroll
    for (int t = 0; t < NT; ++t) {
        const long gr = row_base + t * 32 + ln;
        arow[t] = ((int)(gr >> 14) << 9) + SEG[(int)(gr & 16383)];
    }

    const uint4* AB = (const uint4*)Af;   // 16B units: row*32 + g*16 + u

    // depth-2-mt rolling Af prefetch (16 VGPR): slot = (mt&1)*2
    uint4 Av[4];
    Av[0] = AB[(long)arow[0] * 32 + g * 16 + 0];
    Av[1] = AB[(long)arow[0] * 32 + g * 16 + 1];
    Av[2] = AB[(long)arow[0] * 32 + g * 16 + 2];
    Av[3] = AB[(long)arow[0] * 32 + g * 16 + 3];

    const float4* b24 = (const float4*)B2;
    const float4* w34 = (const float4*)W3;
    const float  b3v  = B3[0];

    #pragma unroll
    for (int t = 0; t < NT; ++t) {
        // ME fragments for this tile (JIT)
        f16x8 mef[4];
        {
            const float4* mb = (const float4*)(ME + (row_base + t*32 + ln) * 64);
            #pragma unroll
            for (int s = 0; s < 4; ++s)
                mef[s] = cvt8(mb[4*s + 2*g], mb[4*s + 2*g + 1]);
        }

        f32x16 acc2[4];
        #pragma unroll
        for (int m2 = 0; m2 < 4; ++m2)
            #pragma unroll
            for (int i = 0; i < 16; ++i) acc2[m2][i] = 0.f;

        #pragma unroll
        for (int mt = 0; mt < 8; ++mt) {
            const int sl = (mt & 1) * 2;
            const uint4 a0 = Av[sl], a1 = Av[sl + 1];
            // refill this slot for linear position L+2 (same rolling slot)
            {
                const int Ln = t * 8 + mt + 2;
                if (Ln < NT * 8) {
                    const int tn = Ln >> 3, mtn = Ln & 7;
                    Av[sl]     = AB[(long)arow[tn] * 32 + g * 16 + 2*mtn];
                    Av[sl + 1] = AB[(long)arow[tn] * 32 + g * 16 + 2*mtn + 1];
                }
            }

            // layer-1 partial: me @ W1b (this mt's 32 cols), pure registers
            f32x16 acc;
            #pragma unroll
            for (int i = 0; i < 16; ++i) acc[i] = 0.f;
            #pragma unroll
            for (int s = 0; s < 4; ++s)
                acc = MFMA32(w1b[mt * 4 + s], mef[s], acc, 0, 0, 0);

            // h1 = relu(A + mw) in packed f16
            u32 hpt[8];
            hpt[0] = pk_relu(pk_add(pack2(acc[0],  acc[1]),  a0.x));
            hpt[1] = pk_relu(pk_add(pack2(acc[2],  acc[3]),  a0.y));
            hpt[2] = pk_relu(pk_add(pack2(acc[4],  acc[5]),  a0.z));
            hpt[3] = pk_relu(pk_add(pack2(acc[6],  acc[7]),  a0.w));
            hpt[4] = pk_relu(pk_add(pack2(acc[8],  acc[9]),  a1.x));
            hpt[5] = pk_relu(pk_add(pack2(acc[10], acc[11]), a1.y));
            hpt[6] = pk_relu(pk_add(pack2(acc[12], acc[13]), a1.z));
            hpt[7] = pk_relu(pk_add(pack2(acc[14], acc[15]), a1.w));

            // layer-2 feed: ks2 = 2*mt + tt, W2 from LDS
            #pragma unroll
            for (int tt = 0; tt < 2; ++tt) {
                u32 w0 = hpt[4*tt+0], w1 = hpt[4*tt+1];
                u32 w2 = hpt[4*tt+2], w3 = hpt[4*tt+3];
                asm("v_permlane32_swap_b32 %0, %1" : "+v"(w0), "+v"(w2));
                asm("v_permlane32_swap_b32 %0, %1" : "+v"(w1), "+v"(w3));
                int wv[4] = {(int)w0, (int)w1, (int)w2, (int)w3};
                f16x8 bf;
                __builtin_memcpy(&bf, wv, 16);
                const int ks2 = 2 * mt + tt;
                __builtin_amdgcn_s_setprio(1);
                #pragma unroll
                for (int m2 = 0; m2 < 4; ++m2)
                    acc2[m2] = MFMA32(sW2[(m2 * 16 + ks2) * 64 + lane], bf, acc2[m2], 0, 0, 0);
                __builtin_amdgcn_s_setprio(0);
            }
        }

        // phase 3: out = relu(h2 + b2) . W3 + b3
        float sum = 0.f;
        #pragma unroll
        for (int m2 = 0; m2 < 4; ++m2)
            #pragma unroll
            for (int q = 0; q < 4; ++q) {
                float4 bb = b24[8*m2 + 2*q + g];
                float4 ww = w34[8*m2 + 2*q + g];
                sum += fmaxf(acc2[m2][4*q+0] + bb.x, 0.f) * ww.x
                     + fmaxf(acc2[m2][4*q+1] + bb.y, 0.f) * ww.y
                     + fmaxf(acc2[m2][4*q+2] + bb.z, 0.f) * ww.z
                     + fmaxf(acc2[m2][4*q+3] + bb.w, 0.f) * ww.w;
            }
        sum += __shfl_xor(sum, 32, 64);     // combine the two g column-halves
        if (lane < 32) OUT[row_base + t * 32 + ln] = sum + b3v;
    }
}

// ---------------------------------------------------------------------------
extern "C" void kernel_launch(void* const* d_in, const int* in_sizes, int n_in,
                              void* d_out, int out_size, void* d_ws, size_t ws_size,
                              hipStream_t stream) {
    const float* h_inst = (const float*)d_in[0];
    const float* me     = (const float*)d_in[1];
    const int*   seg    = (const int*)d_in[2];
    const float* W1     = (const float*)d_in[3];
    const float* b1     = (const float*)d_in[4];
    const float* W2     = (const float*)d_in[5];
    const float* b2     = (const float*)d_in[6];
    const float* W3     = (const float*)d_in[7];
    const float* b3     = (const float*)d_in[8];
    float* out = (float*)d_out;

    char* ws = (char*)d_ws;
    f16* Af   = (f16*)ws;                                   // 8,388,608 B
    f16* pW1a = (f16*)(ws + 8388608);                       //   131,072 B
    f16* pW1b = (f16*)(ws + 8388608 + 131072);              //    32,768 B
    f16* pW2  = (f16*)(ws + 8388608 + 131072 + 32768);      //    65,536 B

    prepack<<<448, 256, 0, stream>>>(W1, W2, pW1a, pW1b, pW2);
    ainit<<<512, 256, 0, stream>>>(h_inst, (const f16x8*)pW1a, b1, Af);
    fused_mlp<<<512, 512, 0, stream>>>(me, seg, Af, (const f16x8*)pW1b,
                                       (const f16x8*)pW2, b2, W3, b3, out);
}

// Round 7
// 83.766 us; speedup vs baseline: 1.5724x; 1.5724x over previous
//
#include <hip/hip_runtime.h>

// B=32, N=512, D=256, M=64, HID=256, H2=128, T=16384, rows R=B*T=524288
typedef _Float16 f16;
typedef f16  f16x2 __attribute__((ext_vector_type(2)));
typedef f16  f16x8 __attribute__((ext_vector_type(8)));
typedef float f32x16 __attribute__((ext_vector_type(16)));
typedef unsigned int u32;

#define MFMA32 __builtin_amdgcn_mfma_f32_32x32x16_f16
#define NT 4   // row-tiles (32 rows) per wave

static __device__ __forceinline__ f16x8 cvt8(float4 a, float4 b) {
    f16x8 v;
    v[0]=(f16)a.x; v[1]=(f16)a.y; v[2]=(f16)a.z; v[3]=(f16)a.w;
    v[4]=(f16)b.x; v[5]=(f16)b.y; v[6]=(f16)b.z; v[7]=(f16)b.w;
    return v;
}
static __device__ __forceinline__ u32 pack2(float a, float b) {
    f16x2 p; p[0]=(f16)a; p[1]=(f16)b;
    return __builtin_bit_cast(u32, p);
}
// packed f16 add / relu (VOP3P)
static __device__ __forceinline__ u32 pk_add(u32 a, u32 b) {
    u32 d; asm("v_pk_add_f16 %0, %1, %2" : "=v"(d) : "v"(a), "v"(b)); return d;
}
static __device__ __forceinline__ u32 pk_relu(u32 a) {
    u32 d; asm("v_pk_max_f16 %0, %1, 0" : "=v"(d) : "v"(a)); return d;
}

// ---------------------------------------------------------------------------
// Prepack: W1a (256x256), W1b (64x256), W2 (256x128) -> f16 MFMA A-operand
// fragment layout for 32x32x16: frag[mt][ks][lane][j] = W[k][col],
// k = 16*ks + 8*(lane>>5) + j, col = 32*mt + (lane&31).
// ---------------------------------------------------------------------------
__global__ __launch_bounds__(256) void prepack(
    const float* __restrict__ W1, const float* __restrict__ W2,
    f16* __restrict__ pa, f16* __restrict__ pb, f16* __restrict__ pc)
{
    const int idx = blockIdx.x * 256 + threadIdx.x;   // grid covers 114688
    int rel, fid, mt, ks;
    const int lane = (idx >> 3) & 63;
    const int j    = idx & 7;
    const int g8   = ((lane >> 5) << 3) + j;          // 8*(lane>>5)+j
    const int ln   = lane & 31;
    if (idx < 65536) {                 // W1a: [8 mt][16 ks]
        rel = idx; fid = rel >> 9; mt = fid >> 4; ks = fid & 15;
        int k = 16 * ks + g8, col = 32 * mt + ln;
        pa[rel] = (f16)W1[k * 256 + col];
    } else if (idx < 81920) {          // W1b: [8 mt][4 ks]
        rel = idx - 65536; fid = rel >> 9; mt = fid >> 2; ks = fid & 3;
        int k = 16 * ks + g8, col = 32 * mt + ln;
        pb[rel] = (f16)W1[(256 + k) * 256 + col];
    } else {                           // W2: [4 mt][16 ks]
        rel = idx - 81920; fid = rel >> 9; mt = fid >> 4; ks = fid & 15;
        int k = 16 * ks + g8, col = 32 * mt + ln;
        pc[rel] = (f16)W2[k * 128 + col];
    }
}

// ---------------------------------------------------------------------------
// Kernel 1: A[ir][c] = sum_k h[ir][k] * W1a[k][c] + b1[c], stored f16 in a
// gather-friendly permuted layout: uint2 index = ir*64 + g*32 + mt*4 + q.
// ---------------------------------------------------------------------------
__global__ __launch_bounds__(256) void ainit(
    const float* __restrict__ H,       // [16384, 256]
    const f16x8* __restrict__ pW1a,    // [8][16][64] frags
    const float* __restrict__ B1,      // [256]
    f16* __restrict__ Af)              // [16384, 256] permuted
{
    const int tid = threadIdx.x, wid = tid >> 6, lane = tid & 63;
    const int g = lane >> 5, ln = lane & 31;
    const long ir = (long)blockIdx.x * 32 + ln;

    const float4* h4 = (const float4*)(H + ir * 256);
    f16x8 hf[16];
    #pragma unroll
    for (int ks = 0; ks < 16; ++ks)
        hf[ks] = cvt8(h4[4 * ks + 2 * g], h4[4 * ks + 2 * g + 1]);

    const float4* b14 = (const float4*)B1;
    #pragma unroll
    for (int mi = 0; mi < 2; ++mi) {
        const int mt = wid * 2 + mi;
        f32x16 acc;
        #pragma unroll
        for (int q = 0; q < 4; ++q) {
            float4 bv = b14[8 * mt + 2 * q + g];
            acc[4*q+0] = bv.x; acc[4*q+1] = bv.y; acc[4*q+2] = bv.z; acc[4*q+3] = bv.w;
        }
        #pragma unroll
        for (int ks = 0; ks < 16; ++ks)
            acc = MFMA32(pW1a[(mt * 16 + ks) * 64 + lane], hf[ks], acc, 0, 0, 0);
        #pragma unroll
        for (int q = 0; q < 4; ++q) {
            uint2 w;
            w.x = pack2(acc[4*q+0], acc[4*q+1]);
            w.y = pack2(acc[4*q+2], acc[4*q+3]);
            ((uint2*)Af)[ir * 64 + g * 32 + mt * 4 + q] = w;
        }
    }
}

// ---------------------------------------------------------------------------
// Fused: h1 = relu(me@W1b + A[seg]); h2 = relu(h1@W2 + b2); out = h2@W3 + b3
// 512 blocks x 8 waves, NT=4 tiles/wave.
//  - W1b (32 KB) + W2 (64 KB) staged to LDS once; barrier-free main loop.
//  - Af prefetched a FULL TILE ahead (Av[16], 64 VGPR, refilled per-mt).
//  - ME refilled in place one tile ahead (Mv[8], 32 VGPR).
//  Budget: ~128 VGPR + 80 AGPR = 208 <= 256 (2 waves/SIMD) -- no spill.
// ---------------------------------------------------------------------------
__global__ __launch_bounds__(512, 2) void fused_mlp(
    const float* __restrict__ ME,      // [524288, 64]
    const int*   __restrict__ SEG,     // [16384]
    const f16*   __restrict__ Af,      // [16384, 256] permuted
    const f16x8* __restrict__ pW1b,    // [8][4][64] frags
    const f16x8* __restrict__ pW2,     // [4][16][64] frags
    const float* __restrict__ B2,      // [128]
    const float* __restrict__ W3,      // [128]
    const float* __restrict__ B3,      // [1]
    float* __restrict__ OUT)           // [524288]
{
    __shared__ f16x8 sW1b[2048];       // 32 KB
    __shared__ f16x8 sW2[4096];        // 64 KB
    const int tid = threadIdx.x, wid = tid >> 6, lane = tid & 63;
    const int g = lane >> 5, ln = lane & 31;

    #pragma unroll
    for (int i = 0; i < 4; ++i) sW1b[i * 512 + tid] = pW1b[i * 512 + tid];
    #pragma unroll
    for (int i = 0; i < 8; ++i) sW2[i * 512 + tid]  = pW2[i * 512 + tid];
    __syncthreads();

    // XCD-bijective block swizzle (512 % 8 == 0)
    const int bswz = (blockIdx.x & 7) * 64 + (blockIdx.x >> 3);
    const long gwave    = (long)bswz * 8 + wid;       // 4096 waves
    const long row_base = gwave * (NT * 32);          // 128 rows per wave

    // segment-gather rows for all NT tiles
    int arow[NT];
    #pragma unroll
    for (int t = 0; t < NT; ++t) {
        const long gr = row_base + t * 32 + ln;
        arow[t] = ((int)(gr >> 14) << 9) + SEG[(int)(gr & 16383)];
    }

    const uint4* AB = (const uint4*)Af;   // 16B units: row*32 + g*16 + u

    // full-tile Af prefetch (64 VGPR) + ME in-place prefetch (32 VGPR)
    uint4 Av[16];
    #pragma unroll
    for (int u = 0; u < 16; ++u) Av[u] = AB[(long)arow[0] * 32 + g * 16 + u];
    float4 Mv[8];
    {
        const float4* mb = (const float4*)(ME + (row_base + ln) * 64);
        #pragma unroll
        for (int s = 0; s < 4; ++s) {
            Mv[2*s]   = mb[4*s + 2*g];
            Mv[2*s+1] = mb[4*s + 2*g + 1];
        }
    }

    const float4* b24 = (const float4*)B2;
    const float4* w34 = (const float4*)W3;
    const float  b3v  = B3[0];

    #pragma unroll
    for (int t = 0; t < NT; ++t) {
        // build ME fragments (consumes Mv), then refill Mv for tile t+1
        f16x8 mef[4];
        #pragma unroll
        for (int s = 0; s < 4; ++s) mef[s] = cvt8(Mv[2*s], Mv[2*s+1]);
        if (t < NT - 1) {
            const float4* mb = (const float4*)(ME + (row_base + (t+1)*32 + ln) * 64);
            #pragma unroll
            for (int s = 0; s < 4; ++s) {
                Mv[2*s]   = mb[4*s + 2*g];
                Mv[2*s+1] = mb[4*s + 2*g + 1];
            }
        }

        f32x16 acc2[4];
        #pragma unroll
        for (int m2 = 0; m2 < 4; ++m2)
            #pragma unroll
            for (int i = 0; i < 16; ++i) acc2[m2][i] = 0.f;

        #pragma unroll
        for (int mt = 0; mt < 8; ++mt) {
            // consume this mt's gathered A chunk, then refill for tile t+1
            const uint4 a0 = Av[2*mt], a1 = Av[2*mt+1];
            if (t < NT - 1) {
                Av[2*mt]   = AB[(long)arow[t+1] * 32 + g * 16 + 2*mt];
                Av[2*mt+1] = AB[(long)arow[t+1] * 32 + g * 16 + 2*mt + 1];
            }

            // layer-1 partial: me @ W1b (this mt's 32 cols), W1b from LDS
            f32x16 acc;
            #pragma unroll
            for (int i = 0; i < 16; ++i) acc[i] = 0.f;
            #pragma unroll
            for (int s = 0; s < 4; ++s)
                acc = MFMA32(sW1b[(mt * 4 + s) * 64 + lane], mef[s], acc, 0, 0, 0);

            // h1 = relu(A + mw) in packed f16
            u32 hpt[8];
            hpt[0] = pk_relu(pk_add(pack2(acc[0],  acc[1]),  a0.x));
            hpt[1] = pk_relu(pk_add(pack2(acc[2],  acc[3]),  a0.y));
            hpt[2] = pk_relu(pk_add(pack2(acc[4],  acc[5]),  a0.z));
            hpt[3] = pk_relu(pk_add(pack2(acc[6],  acc[7]),  a0.w));
            hpt[4] = pk_relu(pk_add(pack2(acc[8],  acc[9]),  a1.x));
            hpt[5] = pk_relu(pk_add(pack2(acc[10], acc[11]), a1.y));
            hpt[6] = pk_relu(pk_add(pack2(acc[12], acc[13]), a1.z));
            hpt[7] = pk_relu(pk_add(pack2(acc[14], acc[15]), a1.w));

            // layer-2 feed: ks2 = 2*mt + tt, W2 from LDS
            #pragma unroll
            for (int tt = 0; tt < 2; ++tt) {
                u32 w0 = hpt[4*tt+0], w1 = hpt[4*tt+1];
                u32 w2 = hpt[4*tt+2], w3 = hpt[4*tt+3];
                asm("v_permlane32_swap_b32 %0, %1" : "+v"(w0), "+v"(w2));
                asm("v_permlane32_swap_b32 %0, %1" : "+v"(w1), "+v"(w3));
                int wv[4] = {(int)w0, (int)w1, (int)w2, (int)w3};
                f16x8 bf;
                __builtin_memcpy(&bf, wv, 16);
                const int ks2 = 2 * mt + tt;
                __builtin_amdgcn_s_setprio(1);
                #pragma unroll
                for (int m2 = 0; m2 < 4; ++m2)
                    acc2[m2] = MFMA32(sW2[(m2 * 16 + ks2) * 64 + lane], bf, acc2[m2], 0, 0, 0);
                __builtin_amdgcn_s_setprio(0);
            }
        }

        // phase 3: out = relu(h2 + b2) . W3 + b3
        float sum = 0.f;
        #pragma unroll
        for (int m2 = 0; m2 < 4; ++m2)
            #pragma unroll
            for (int q = 0; q < 4; ++q) {
                float4 bb = b24[8*m2 + 2*q + g];
                float4 ww = w34[8*m2 + 2*q + g];
                sum += fmaxf(acc2[m2][4*q+0] + bb.x, 0.f) * ww.x
                     + fmaxf(acc2[m2][4*q+1] + bb.y, 0.f) * ww.y
                     + fmaxf(acc2[m2][4*q+2] + bb.z, 0.f) * ww.z
                     + fmaxf(acc2[m2][4*q+3] + bb.w, 0.f) * ww.w;
            }
        sum += __shfl_xor(sum, 32, 64);     // combine the two g column-halves
        if (lane < 32) OUT[row_base + t * 32 + ln] = sum + b3v;
    }
}

// ---------------------------------------------------------------------------
extern "C" void kernel_launch(void* const* d_in, const int* in_sizes, int n_in,
                              void* d_out, int out_size, void* d_ws, size_t ws_size,
                              hipStream_t stream) {
    const float* h_inst = (const float*)d_in[0];
    const float* me     = (const float*)d_in[1];
    const int*   seg    = (const int*)d_in[2];
    const float* W1     = (const float*)d_in[3];
    const float* b1     = (const float*)d_in[4];
    const float* W2     = (const float*)d_in[5];
    const float* b2     = (const float*)d_in[6];
    const float* W3     = (const float*)d_in[7];
    const float* b3     = (const float*)d_in[8];
    float* out = (float*)d_out;

    char* ws = (char*)d_ws;
    f16* Af   = (f16*)ws;                                   // 8,388,608 B
    f16* pW1a = (f16*)(ws + 8388608);                       //   131,072 B
    f16* pW1b = (f16*)(ws + 8388608 + 131072);              //    32,768 B
    f16* pW2  = (f16*)(ws + 8388608 + 131072 + 32768);      //    65,536 B

    prepack<<<448, 256, 0, stream>>>(W1, W2, pW1a, pW1b, pW2);
    ainit<<<512, 256, 0, stream>>>(h_inst, (const f16x8*)pW1a, b1, Af);
    fused_mlp<<<512, 512, 0, stream>>>(me, seg, Af, (const f16x8*)pW1b,
                                       (const f16x8*)pW2, b2, W3, b3, out);
}

// Round 9
// 83.098 us; speedup vs baseline: 1.5851x; 1.0080x over previous
//
#include <hip/hip_runtime.h>

// B=32, N=512, D=256, M=64, HID=256, H2=128, T=16384, rows R=B*T=524288
typedef _Float16 f16;
typedef f16  f16x2 __attribute__((ext_vector_type(2)));
typedef f16  f16x8 __attribute__((ext_vector_type(8)));
typedef float f32x16 __attribute__((ext_vector_type(16)));
typedef unsigned int u32;

#define MFMA32 __builtin_amdgcn_mfma_f32_32x32x16_f16
#define NT 4   // row-tiles (32 rows) per wave

static __device__ __forceinline__ f16x8 cvt8(float4 a, float4 b) {
    f16x8 v;
    v[0]=(f16)a.x; v[1]=(f16)a.y; v[2]=(f16)a.z; v[3]=(f16)a.w;
    v[4]=(f16)b.x; v[5]=(f16)b.y; v[6]=(f16)b.z; v[7]=(f16)b.w;
    return v;
}
static __device__ __forceinline__ u32 pack2(float a, float b) {
    f16x2 p; p[0]=(f16)a; p[1]=(f16)b;
    return __builtin_bit_cast(u32, p);
}
static __device__ __forceinline__ u32 pk_add(u32 a, u32 b) {
    u32 d; asm("v_pk_add_f16 %0, %1, %2" : "=v"(d) : "v"(a), "v"(b)); return d;
}
static __device__ __forceinline__ u32 pk_relu(u32 a) {
    u32 d; asm("v_pk_max_f16 %0, %1, 0" : "=v"(d) : "v"(a)); return d;
}

// ---------------------------------------------------------------------------
// Prepack: W1a (256x256), W1b (64x256), W2 (256x128) -> f16 MFMA A-operand
// fragment layout for 32x32x16: frag[mt][ks][lane][j] = W[k][col],
// k = 16*ks + 8*(lane>>5) + j, col = 32*mt + (lane&31).
// ---------------------------------------------------------------------------
__global__ __launch_bounds__(256) void prepack(
    const float* __restrict__ W1, const float* __restrict__ W2,
    f16* __restrict__ pa, f16* __restrict__ pb, f16* __restrict__ pc)
{
    const int idx = blockIdx.x * 256 + threadIdx.x;   // grid covers 114688
    int rel, fid, mt, ks;
    const int lane = (idx >> 3) & 63;
    const int j    = idx & 7;
    const int g8   = ((lane >> 5) << 3) + j;
    const int ln   = lane & 31;
    if (idx < 65536) {                 // W1a: [8 mt][16 ks]
        rel = idx; fid = rel >> 9; mt = fid >> 4; ks = fid & 15;
        int k = 16 * ks + g8, col = 32 * mt + ln;
        pa[rel] = (f16)W1[k * 256 + col];
    } else if (idx < 81920) {          // W1b: [8 mt][4 ks]
        rel = idx - 65536; fid = rel >> 9; mt = fid >> 2; ks = fid & 3;
        int k = 16 * ks + g8, col = 32 * mt + ln;
        pb[rel] = (f16)W1[(256 + k) * 256 + col];
    } else {                           // W2: [4 mt][16 ks]
        rel = idx - 81920; fid = rel >> 9; mt = fid >> 4; ks = fid & 15;
        int k = 16 * ks + g8, col = 32 * mt + ln;
        pc[rel] = (f16)W2[k * 128 + col];
    }
}

// ---------------------------------------------------------------------------
// Kernel 1: A[ir][c] = sum_k h[ir][k] * W1a[k][c] + b1[c], stored f16 in a
// gather-friendly permuted layout: uint2 index = ir*64 + g*32 + mt*4 + q.
// ---------------------------------------------------------------------------
__global__ __launch_bounds__(256) void ainit(
    const float* __restrict__ H,       // [16384, 256]
    const f16x8* __restrict__ pW1a,    // [8][16][64] frags
    const float* __restrict__ B1,      // [256]
    f16* __restrict__ Af)              // [16384, 256] permuted
{
    const int tid = threadIdx.x, wid = tid >> 6, lane = tid & 63;
    const int g = lane >> 5, ln = lane & 31;
    const long ir = (long)blockIdx.x * 32 + ln;

    const float4* h4 = (const float4*)(H + ir * 256);
    f16x8 hf[16];
    #pragma unroll
    for (int ks = 0; ks < 16; ++ks)
        hf[ks] = cvt8(h4[4 * ks + 2 * g], h4[4 * ks + 2 * g + 1]);

    const float4* b14 = (const float4*)B1;
    #pragma unroll
    for (int mi = 0; mi < 2; ++mi) {
        const int mt = wid * 2 + mi;
        f32x16 acc;
        #pragma unroll
        for (int q = 0; q < 4; ++q) {
            float4 bv = b14[8 * mt + 2 * q + g];
            acc[4*q+0] = bv.x; acc[4*q+1] = bv.y; acc[4*q+2] = bv.z; acc[4*q+3] = bv.w;
        }
        #pragma unroll
        for (int ks = 0; ks < 16; ++ks)
            acc = MFMA32(pW1a[(mt * 16 + ks) * 64 + lane], hf[ks], acc, 0, 0, 0);
        #pragma unroll
        for (int q = 0; q < 4; ++q) {
            uint2 w;
            w.x = pack2(acc[4*q+0], acc[4*q+1]);
            w.y = pack2(acc[4*q+2], acc[4*q+3]);
            ((uint2*)Af)[ir * 64 + g * 32 + mt * 4 + q] = w;
        }
    }
}

// ---------------------------------------------------------------------------
// Fused kernel. All global traffic COALESCED:
//  - ME: 8 coalesced float4 loads per tile, f16-packed, LDS-bounced.
//  - Af: <=3 distinct gather rows per 32-row tile (segment runs >= 8);
//    boundaries via __ballot; each 512B row = ONE coalesced uint2 load;
//    staged to per-wave LDS slots; lanes read their chunk via LDS.
//    slot(ln) = popc(boundaries at positions <= ln) - 1   [R8 bug: was <ln]
//  - W1b (32KB) + W2 (64KB) in LDS. No barriers in the main loop.
// ---------------------------------------------------------------------------
__global__ __launch_bounds__(512, 2) void fused_mlp(
    const float* __restrict__ ME,      // [524288, 64]
    const int*   __restrict__ SEG,     // [16384]
    const f16*   __restrict__ Af,      // [16384, 256] permuted
    const f16x8* __restrict__ pW1b,    // [8][4][64] frags
    const f16x8* __restrict__ pW2,     // [4][16][64] frags
    const float* __restrict__ B2,      // [128]
    const float* __restrict__ W3,      // [128]
    const float* __restrict__ B3,      // [1]
    float* __restrict__ OUT)           // [524288]
{
    __shared__ f16x8 sW1b[2048];       // 32 KB
    __shared__ f16x8 sW2[4096];        // 64 KB
    __shared__ uint2 sME[8][512];      // 8 waves x 4 KB (f16 tile, frag order)
    __shared__ uint2 sAf[8][256];      // 8 waves x 2 KB (slots x 512 B)

    const int tid = threadIdx.x, wid = tid >> 6, lane = tid & 63;
    const int g = lane >> 5, ln = lane & 31;

    #pragma unroll
    for (int i = 0; i < 4; ++i) sW1b[i * 512 + tid] = pW1b[i * 512 + tid];
    #pragma unroll
    for (int i = 0; i < 8; ++i) sW2[i * 512 + tid]  = pW2[i * 512 + tid];
    __syncthreads();

    // XCD-bijective block swizzle (512 % 8 == 0)
    const int bswz = (blockIdx.x & 7) * 64 + (blockIdx.x >> 3);
    const long gwave    = (long)bswz * 8 + wid;       // 4096 waves
    const long row_base = gwave * (NT * 32);          // 128 rows, same batch b
    const int  b     = (int)(row_base >> 14);
    const int  tloc0 = (int)(row_base & 16383);

    // ---- gather metadata per tile: <=3 distinct Af rows (segment runs >=8)
    int r0a[NT], r1a[NT], r2a[NT];     // uniform distinct row ids
    int slot[NT];                      // per-lane slot index (0..2)
    #pragma unroll
    for (int t = 0; t < NT; ++t) {
        const int ar   = SEG[tloc0 + t * 32 + ln];
        const int prev = __shfl_up(ar, 1);
        const u32 mk = (u32)__ballot((ln == 0) || (ar != prev));  // low 32 lanes
        u32 m = mk;
        const int p0 = __builtin_ctz(m); m &= m - 1;
        const int p1 = m ? __builtin_ctz(m) : p0; m &= m - 1;
        const int p2 = m ? __builtin_ctz(m) : p1;
        const int base = b << 9;
        r0a[t] = base + __builtin_amdgcn_readlane(ar, p0);
        r1a[t] = base + __builtin_amdgcn_readlane(ar, p1);
        r2a[t] = base + __builtin_amdgcn_readlane(ar, p2);
        // rank of this lane's run = (# boundaries at positions <= ln) - 1
        slot[t] = __popc(mk & ((2u << ln) - 1)) - 1;
    }

    const uint2* AB8 = (const uint2*)Af;   // 8B units: row*64 + u

    // ME write offset (uint2 units): lane holds fp32 chunk c=(l&15) of row
    // r=4i+(l>>4); f16 dest unit ((c>>1)*32 + r)*2 + (c&1).
    const int meW = (((lane & 15) >> 1) * 32 + (lane >> 4)) * 2 + (lane & 1);

    float4 mv[8]; uint2 av[3];
    #define ISSUE(t_) {                                                      \
        const float4* mb = (const float4*)(ME + (row_base + (t_) * 32) * 64);\
        _Pragma("unroll")                                                    \
        for (int i = 0; i < 8; ++i) mv[i] = mb[i * 64 + lane];               \
        av[0] = AB8[(long)r0a[t_] * 64 + lane];                              \
        av[1] = AB8[(long)r1a[t_] * 64 + lane];                              \
        av[2] = AB8[(long)r2a[t_] * 64 + lane];                              \
    }
    #define COMMIT() {                                                       \
        _Pragma("unroll")                                                    \
        for (int i = 0; i < 8; ++i) {                                        \
            uint2 w;                                                         \
            w.x = pack2(mv[i].x, mv[i].y);                                   \
            w.y = pack2(mv[i].z, mv[i].w);                                   \
            sME[wid][meW + i * 8] = w;                                       \
        }                                                                    \
        sAf[wid][0 * 64 + lane] = av[0];                                     \
        sAf[wid][1 * 64 + lane] = av[1];                                     \
        sAf[wid][2 * 64 + lane] = av[2];                                     \
    }

    ISSUE(0);
    COMMIT();

    const float4* b24 = (const float4*)B2;
    const float4* w34 = (const float4*)W3;
    const float  b3v  = B3[0];

    #pragma unroll
    for (int t = 0; t < NT; ++t) {
        if (t + 1 < NT) ISSUE(t + 1);          // covered by this tile's compute

        // ME fragments from LDS (conflict-free lane-linear b128)
        f16x8 mef[4];
        #pragma unroll
        for (int s = 0; s < 4; ++s)
            mef[s] = *(const f16x8*)&sME[wid][((2 * s + g) * 32 + ln) * 2];

        const uint4* afp = (const uint4*)&sAf[wid][0];   // 16B units
        const int afbase = slot[t] * 32 + g * 16;

        f32x16 acc2[4];
        #pragma unroll
        for (int m2 = 0; m2 < 4; ++m2)
            #pragma unroll
            for (int i = 0; i < 16; ++i) acc2[m2][i] = 0.f;

        #pragma unroll
        for (int mt = 0; mt < 8; ++mt) {
            const uint4 a0 = afp[afbase + 2 * mt];
            const uint4 a1 = afp[afbase + 2 * mt + 1];

            f32x16 acc;
            #pragma unroll
            for (int i = 0; i < 16; ++i) acc[i] = 0.f;
            #pragma unroll
            for (int s = 0; s < 4; ++s)
                acc = MFMA32(sW1b[(mt * 4 + s) * 64 + lane], mef[s], acc, 0, 0, 0);

            u32 hpt[8];
            hpt[0] = pk_relu(pk_add(pack2(acc[0],  acc[1]),  a0.x));
            hpt[1] = pk_relu(pk_add(pack2(acc[2],  acc[3]),  a0.y));
            hpt[2] = pk_relu(pk_add(pack2(acc[4],  acc[5]),  a0.z));
            hpt[3] = pk_relu(pk_add(pack2(acc[6],  acc[7]),  a0.w));
            hpt[4] = pk_relu(pk_add(pack2(acc[8],  acc[9]),  a1.x));
            hpt[5] = pk_relu(pk_add(pack2(acc[10], acc[11]), a1.y));
            hpt[6] = pk_relu(pk_add(pack2(acc[12], acc[13]), a1.z));
            hpt[7] = pk_relu(pk_add(pack2(acc[14], acc[15]), a1.w));

            #pragma unroll
            for (int tt = 0; tt < 2; ++tt) {
                u32 w0 = hpt[4*tt+0], w1 = hpt[4*tt+1];
                u32 w2 = hpt[4*tt+2], w3 = hpt[4*tt+3];
                asm("v_permlane32_swap_b32 %0, %1" : "+v"(w0), "+v"(w2));
                asm("v_permlane32_swap_b32 %0, %1" : "+v"(w1), "+v"(w3));
                int wv[4] = {(int)w0, (int)w1, (int)w2, (int)w3};
                f16x8 bf;
                __builtin_memcpy(&bf, wv, 16);
                const int ks2 = 2 * mt + tt;
                __builtin_amdgcn_s_setprio(1);
                #pragma unroll
                for (int m2 = 0; m2 < 4; ++m2)
                    acc2[m2] = MFMA32(sW2[(m2 * 16 + ks2) * 64 + lane], bf, acc2[m2], 0, 0, 0);
                __builtin_amdgcn_s_setprio(0);
            }
        }

        // phase 3: out = relu(h2 + b2) . W3 + b3
        float sum = 0.f;
        #pragma unroll
        for (int m2 = 0; m2 < 4; ++m2)
            #pragma unroll
            for (int q = 0; q < 4; ++q) {
                float4 bb = b24[8*m2 + 2*q + g];
                float4 ww = w34[8*m2 + 2*q + g];
                sum += fmaxf(acc2[m2][4*q+0] + bb.x, 0.f) * ww.x
                     + fmaxf(acc2[m2][4*q+1] + bb.y, 0.f) * ww.y
                     + fmaxf(acc2[m2][4*q+2] + bb.z, 0.f) * ww.z
                     + fmaxf(acc2[m2][4*q+3] + bb.w, 0.f) * ww.w;
            }
        sum += __shfl_xor(sum, 32, 64);
        if (lane < 32) OUT[row_base + t * 32 + ln] = sum + b3v;

        if (t + 1 < NT) COMMIT();              // stage next tile's LDS data
    }
    #undef ISSUE
    #undef COMMIT
}

// ---------------------------------------------------------------------------
extern "C" void kernel_launch(void* const* d_in, const int* in_sizes, int n_in,
                              void* d_out, int out_size, void* d_ws, size_t ws_size,
                              hipStream_t stream) {
    const float* h_inst = (const float*)d_in[0];
    const float* me     = (const float*)d_in[1];
    const int*   seg    = (const int*)d_in[2];
    const float* W1     = (const float*)d_in[3];
    const float* b1     = (const float*)d_in[4];
    const float* W2     = (const float*)d_in[5];
    const float* b2     = (const float*)d_in[6];
    const float* W3     = (const float*)d_in[7];
    const float* b3     = (const float*)d_in[8];
    float* out = (float*)d_out;

    char* ws = (char*)d_ws;
    f16* Af   = (f16*)ws;                                   // 8,388,608 B
    f16* pW1a = (f16*)(ws + 8388608);                       //   131,072 B
    f16* pW1b = (f16*)(ws + 8388608 + 131072);              //    32,768 B
    f16* pW2  = (f16*)(ws + 8388608 + 131072 + 32768);      //    65,536 B

    prepack<<<448, 256, 0, stream>>>(W1, W2, pW1a, pW1b, pW2);
    ainit<<<512, 256, 0, stream>>>(h_inst, (const f16x8*)pW1a, b1, Af);
    fused_mlp<<<512, 512, 0, stream>>>(me, seg, Af, (const f16x8*)pW1b,
                                       (const f16x8*)pW2, b2, W3, b3, out);
}